// Round 14
// baseline (643.272 us; speedup 1.0000x reference)
//
#include <hip/hip_runtime.h>
#include <hip/hip_bf16.h>

// MoE layer, MI355X gfx950. B=16, C=64, H=W=128, E=8, TOPK=2.
// out = x + sum_{s in top2} w_s * (W2_e @ gelu((W1_e @ x + b1_e) * k) + b2_e)
// Single fused kernel: per-block x staging + pool partials; last-arriving
// block per batch computes gate (atomic counter, no grid sync); per-batch
// flag release; then round-9-proven MFMA pipeline. x read from HBM once.

#define BB 16
#define CC 64
#define EE 8
#define HWPX 16384

typedef __bf16 bf16x8 __attribute__((ext_vector_type(8)));
typedef float f32x4 __attribute__((ext_vector_type(4)));

__device__ __forceinline__ unsigned packbf2(float lo, float hi) {
    // compiler emits v_cvt_pk_bf16_f32 (RNE)
    __bf16 a = (__bf16)lo, b = (__bf16)hi;
    unsigned short ua = __builtin_bit_cast(unsigned short, a);
    unsigned short ub = __builtin_bit_cast(unsigned short, b);
    return ((unsigned)ub << 16) | (unsigned)ua;
}

// XOR-swizzled dword index into a [64 px][32 dword] LDS tile.
__device__ __forceinline__ int swz(int px, int d) {
    return px * 32 + ((d & ~3) ^ ((px & 7) << 2)) + (d & 3);
}

__device__ __forceinline__ bf16x8 cvt8(float4 u, float4 v) {
    uint4 d;
    d.x = packbf2(u.x, u.y); d.y = packbf2(u.z, u.w);
    d.z = packbf2(v.x, v.y); d.w = packbf2(v.z, v.w);
    return __builtin_bit_cast(bf16x8, d);
}
__device__ __forceinline__ float4 ld4(const float* p) { return *(const float4*)p; }

// ================= fused single kernel =================
// Grid: 4096 blocks; ticket-remapped vbid -> (batch b = vbid>>8, tile = vbid&255).
// Block: 256 thr = 4 waves; wave w owns output ch 16w..16w+15 for 64 px.
__global__ __launch_bounds__(256, 4) void moe_fused(
    const float* __restrict__ x, const float* __restrict__ kvec,
    const float* __restrict__ Wg, const float* __restrict__ bg,
    const float* __restrict__ W1, const float* __restrict__ b1,
    const float* __restrict__ W2, const float* __restrict__ b2,
    float* __restrict__ out,
    unsigned* __restrict__ tick, unsigned* __restrict__ cnt,   // cnt stride 16 dwords
    unsigned* __restrict__ flag,                               // stride 16 dwords
    int* __restrict__ gidx, float* __restrict__ gw,
    float* __restrict__ partial) {                             // [4096][64]

    __shared__ unsigned LX[64 * 32];
    __shared__ unsigned LH0[64 * 32];
    __shared__ unsigned LH1[64 * 32];
    __shared__ unsigned bc[8];

    const int t = threadIdx.x;
    const int w = t >> 6, l = t & 63, g = l >> 4, l15 = l & 15;
    const int arow = 16 * w + l15;     // A-fragment row (out channel)
    const int r0w = 16 * w + 4 * g;    // this lane's first owned channel
    const int d0 = 8 * w + 2 * g;      // LDS dword col of ch pair base

    // ---- ticket: virtual block id in scheduling order ----
    if (t == 0)
        bc[0] = __hip_atomic_fetch_add(tick, 1u, __ATOMIC_RELAXED, __HIP_MEMORY_SCOPE_AGENT);
    __syncthreads();
    const int vbid = (int)bc[0];
    const int b = vbid >> 8;
    const int P0 = (vbid & 255) << 6;

    // ---- phase 1: load own 16 x values (f32 residual), stage LDS, pool partial ----
    const float* xb = x + b * CC * HWPX;
    const int obase = r0w * HWPX + P0 + l15;
    float xc[16];
    #pragma unroll
    for (int cb = 0; cb < 4; ++cb)
        #pragma unroll
        for (int j = 0; j < 4; ++j)
            xc[cb * 4 + j] = xb[obase + j * HWPX + cb * 16];

    #pragma unroll
    for (int cb = 0; cb < 4; ++cb) {
        uint2 pk;
        pk.x = packbf2(xc[cb * 4 + 0], xc[cb * 4 + 1]);
        pk.y = packbf2(xc[cb * 4 + 2], xc[cb * 4 + 3]);
        *(uint2*)&LX[swz(cb * 16 + l15, d0)] = pk;
    }

    {   // per-channel partial sums over this tile's 64 px
        float pj[4];
        #pragma unroll
        for (int j = 0; j < 4; ++j)
            pj[j] = (xc[j] + xc[4 + j]) + (xc[8 + j] + xc[12 + j]);
        #pragma unroll
        for (int m = 1; m < 16; m <<= 1)
            #pragma unroll
            for (int j = 0; j < 4; ++j) pj[j] += __shfl_xor(pj[j], m);
        if (l15 == 0) {
            f32x4 v = {pj[0], pj[1], pj[2], pj[3]};
            *(f32x4*)&partial[vbid * 64 + r0w] = v;
        }
    }
    __syncthreads();   // partial stores + LX staged (bar A)

    if (t == 0) {
        __threadfence();
        unsigned old = __hip_atomic_fetch_add(&cnt[b * 16], 1u, __ATOMIC_ACQ_REL, __HIP_MEMORY_SCOPE_AGENT);
        bc[1] = (old == 255u) ? 1u : 0u;
    }
    __syncthreads();

    // ---- last arriver of batch b computes the gate ----
    if (bc[1]) {
        float* gs = (float*)LH0;
        const float* pb = partial + (size_t)((b << 8) + (w << 6)) * 64 + l;
        float s = 0.f;
        #pragma unroll 8
        for (int i = 0; i < 64; ++i)
            s += __hip_atomic_load(pb + i * 64, __ATOMIC_RELAXED, __HIP_MEMORY_SCOPE_AGENT);
        gs[(w << 6) + l] = s;
        __syncthreads();
        if (w == 0) {
            float pv = ((gs[l] + gs[64 + l]) + (gs[128 + l] + gs[192 + l])) * (1.0f / 16384.f);
            f32x4 wgA = *(const f32x4*)(Wg + l * EE);
            f32x4 wgB = *(const f32x4*)(Wg + l * EE + 4);
            float le[EE] = {pv * wgA[0], pv * wgA[1], pv * wgA[2], pv * wgA[3],
                            pv * wgB[0], pv * wgB[1], pv * wgB[2], pv * wgB[3]};
            #pragma unroll
            for (int m = 1; m < 64; m <<= 1)
                #pragma unroll
                for (int e = 0; e < EE; ++e) le[e] += __shfl_xor(le[e], m);
            if (l == 0) {
                float lg[EE];
                float mx = -1e30f;
                #pragma unroll
                for (int e = 0; e < EE; ++e) { lg[e] = le[e] + bg[e]; mx = fmaxf(mx, lg[e]); }
                float den = 0.f;
                #pragma unroll
                for (int e = 0; e < EE; ++e) { lg[e] = expf(lg[e] - mx); den += lg[e]; }
                float inv = 1.0f / den;
                float m0 = lg[0] * inv; int i0 = 0;
                #pragma unroll
                for (int e = 1; e < EE; ++e) {
                    float v = lg[e] * inv;
                    if (v > m0) { m0 = v; i0 = e; }
                }
                float m1 = -1.f; int i1 = 0;
                #pragma unroll
                for (int e = 0; e < EE; ++e) {
                    float v = lg[e] * inv;
                    if (e != i0 && v > m1) { m1 = v; i1 = e; }
                }
                gidx[b * 2 + 0] = i0; gidx[b * 2 + 1] = i1;
                gw[b * 2 + 0] = m0;  gw[b * 2 + 1] = m1;
                __threadfence();
                __hip_atomic_store(&flag[b * 16], 1u, __ATOMIC_RELEASE, __HIP_MEMORY_SCOPE_AGENT);
            }
        }
        __syncthreads();   // LH0 scratch free again
    }

    // ---- wait for this batch's gate ----
    if (t == 0) {
        while (__hip_atomic_load(&flag[b * 16], __ATOMIC_ACQUIRE, __HIP_MEMORY_SCOPE_AGENT) == 0u)
            __builtin_amdgcn_s_sleep(2);
        bc[2] = (unsigned)__hip_atomic_load(&gidx[b * 2 + 0], __ATOMIC_RELAXED, __HIP_MEMORY_SCOPE_AGENT);
        bc[3] = (unsigned)__hip_atomic_load(&gidx[b * 2 + 1], __ATOMIC_RELAXED, __HIP_MEMORY_SCOPE_AGENT);
        float f0 = __hip_atomic_load(&gw[b * 2 + 0], __ATOMIC_RELAXED, __HIP_MEMORY_SCOPE_AGENT);
        float f1 = __hip_atomic_load(&gw[b * 2 + 1], __ATOMIC_RELAXED, __HIP_MEMORY_SCOPE_AGENT);
        bc[4] = __builtin_bit_cast(unsigned, f0);
        bc[5] = __builtin_bit_cast(unsigned, f1);
    }
    __syncthreads();
    const int e0 = __builtin_amdgcn_readfirstlane((int)bc[2]);
    const int e1 = __builtin_amdgcn_readfirstlane((int)bc[3]);
    const float wgt0 = __builtin_bit_cast(float, bc[4]);
    const float wgt1 = __builtin_bit_cast(float, bc[5]);

    // gelu sigmoid-form: gelu(t) = t * rcp(1 + exp2(t*(C1 + C2*t^2)))
    const float C1 = -2.302208239f;    // -2*log2(e)*0.7978845608
    const float C2 = -0.1029434f;      // C1 * 0.044715

    const int wrow = arow * CC;
    const f32x4 kk = *(const f32x4*)(kvec + b * CC + r0w);

    // ---- GEMM1 expert0 (weights f32 -> bf16 in-register, L3-hot) ----
    const float* W1e0 = W1 + e0 * CC * CC;
    bf16x8 a1k0 = cvt8(ld4(W1e0 + wrow + g * 8), ld4(W1e0 + wrow + g * 8 + 4));
    bf16x8 a1k1 = cvt8(ld4(W1e0 + wrow + 32 + g * 8), ld4(W1e0 + wrow + 32 + g * 8 + 4));
    const f32x4 b1v0 = *(const f32x4*)(b1 + e0 * CC + r0w);
    f32x4 h[4];
    #pragma unroll
    for (int cb = 0; cb < 4; ++cb) {
        bf16x8 bx0 = *(const bf16x8*)&LX[swz(cb * 16 + l15, g * 4)];
        bf16x8 bx1 = *(const bf16x8*)&LX[swz(cb * 16 + l15, 16 + g * 4)];
        h[cb] = (f32x4){0.f, 0.f, 0.f, 0.f};
        h[cb] = __builtin_amdgcn_mfma_f32_16x16x32_bf16(a1k0, bx0, h[cb], 0, 0, 0);
        h[cb] = __builtin_amdgcn_mfma_f32_16x16x32_bf16(a1k1, bx1, h[cb], 0, 0, 0);
    }
    uint2 pk0[4];
    #pragma unroll
    for (int cb = 0; cb < 4; ++cb) {
        float hv[4];
        #pragma unroll
        for (int j = 0; j < 4; ++j) {
            float tt = (h[cb][j] + b1v0[j]) * kk[j];
            float ex = __builtin_amdgcn_exp2f(tt * fmaf(C2, tt * tt, C1));
            hv[j] = (tt * wgt0) * __builtin_amdgcn_rcpf(ex + 1.f);
        }
        pk0[cb].x = packbf2(hv[0], hv[1]);
        pk0[cb].y = packbf2(hv[2], hv[3]);
    }

    // ---- GEMM1 expert1 (reuses h regs) ----
    const float* W1e1 = W1 + e1 * CC * CC;
    a1k0 = cvt8(ld4(W1e1 + wrow + g * 8), ld4(W1e1 + wrow + g * 8 + 4));
    a1k1 = cvt8(ld4(W1e1 + wrow + 32 + g * 8), ld4(W1e1 + wrow + 32 + g * 8 + 4));
    const f32x4 b1v1 = *(const f32x4*)(b1 + e1 * CC + r0w);
    #pragma unroll
    for (int cb = 0; cb < 4; ++cb) {
        bf16x8 bx0 = *(const bf16x8*)&LX[swz(cb * 16 + l15, g * 4)];
        bf16x8 bx1 = *(const bf16x8*)&LX[swz(cb * 16 + l15, 16 + g * 4)];
        h[cb] = (f32x4){0.f, 0.f, 0.f, 0.f};
        h[cb] = __builtin_amdgcn_mfma_f32_16x16x32_bf16(a1k0, bx0, h[cb], 0, 0, 0);
        h[cb] = __builtin_amdgcn_mfma_f32_16x16x32_bf16(a1k1, bx1, h[cb], 0, 0, 0);
    }
    uint2 pk1[4];
    #pragma unroll
    for (int cb = 0; cb < 4; ++cb) {
        float hv[4];
        #pragma unroll
        for (int j = 0; j < 4; ++j) {
            float tt = (h[cb][j] + b1v1[j]) * kk[j];
            float ex = __builtin_amdgcn_exp2f(tt * fmaf(C2, tt * tt, C1));
            hv[j] = (tt * wgt1) * __builtin_amdgcn_rcpf(ex + 1.f);
        }
        pk1[cb].x = packbf2(hv[0], hv[1]);
        pk1[cb].y = packbf2(hv[2], hv[3]);
    }

    // ---- write hT0/hT1; prepare W2 frags + b2 while writes land ----
    #pragma unroll
    for (int cb = 0; cb < 4; ++cb) {
        *(uint2*)&LH0[swz(cb * 16 + l15, d0)] = pk0[cb];
        *(uint2*)&LH1[swz(cb * 16 + l15, d0)] = pk1[cb];
    }
    const float* W2e0 = W2 + e0 * CC * CC;
    const float* W2e1 = W2 + e1 * CC * CC;
    bf16x8 a2e0k0 = cvt8(ld4(W2e0 + wrow + g * 8), ld4(W2e0 + wrow + g * 8 + 4));
    bf16x8 a2e0k1 = cvt8(ld4(W2e0 + wrow + 32 + g * 8), ld4(W2e0 + wrow + 32 + g * 8 + 4));
    bf16x8 a2e1k0 = cvt8(ld4(W2e1 + wrow + g * 8), ld4(W2e1 + wrow + g * 8 + 4));
    bf16x8 a2e1k1 = cvt8(ld4(W2e1 + wrow + 32 + g * 8), ld4(W2e1 + wrow + 32 + g * 8 + 4));
    const f32x4 b2v0 = *(const f32x4*)(b2 + e0 * CC + r0w);
    const f32x4 b2v1 = *(const f32x4*)(b2 + e1 * CC + r0w);
    float bsum[4];
    #pragma unroll
    for (int j = 0; j < 4; ++j) bsum[j] = fmaf(wgt0, b2v0[j], wgt1 * b2v1[j]);

    __syncthreads();   // bar B: hT0 + hT1 visible

    // ---- GEMM2 both experts ----
    f32x4 acc[4];
    #pragma unroll
    for (int cb = 0; cb < 4; ++cb) {
        acc[cb] = (f32x4){0.f, 0.f, 0.f, 0.f};
        bf16x8 bh0 = *(const bf16x8*)&LH0[swz(cb * 16 + l15, g * 4)];
        bf16x8 bh1 = *(const bf16x8*)&LH0[swz(cb * 16 + l15, 16 + g * 4)];
        acc[cb] = __builtin_amdgcn_mfma_f32_16x16x32_bf16(a2e0k0, bh0, acc[cb], 0, 0, 0);
        acc[cb] = __builtin_amdgcn_mfma_f32_16x16x32_bf16(a2e0k1, bh1, acc[cb], 0, 0, 0);
        bf16x8 bg0 = *(const bf16x8*)&LH1[swz(cb * 16 + l15, g * 4)];
        bf16x8 bg1 = *(const bf16x8*)&LH1[swz(cb * 16 + l15, 16 + g * 4)];
        acc[cb] = __builtin_amdgcn_mfma_f32_16x16x32_bf16(a2e1k0, bg0, acc[cb], 0, 0, 0);
        acc[cb] = __builtin_amdgcn_mfma_f32_16x16x32_bf16(a2e1k1, bg1, acc[cb], 0, 0, 0);
    }

    // ---- epilogue: out = x(f32 regs) + acc + gated b2 ----
    float* ob = out + b * CC * HWPX;
    #pragma unroll
    for (int cb = 0; cb < 4; ++cb)
        #pragma unroll
        for (int j = 0; j < 4; ++j)
            ob[obase + j * HWPX + cb * 16] = xc[cb * 4 + j] + (acc[cb][j] + bsum[j]);
}

// ================= fallback path (round-9, proven 51.5 us) =================
__global__ __launch_bounds__(256) void pool_conv_kernel(
    const float* __restrict__ x, float* __restrict__ pooled,
    const float* __restrict__ W1, const float* __restrict__ W2,
    __bf16* __restrict__ W1b, __bf16* __restrict__ W2b) {
    int blk = blockIdx.x;
    if (blk < BB * CC) {
        const float4* p = (const float4*)(x + (size_t)blk * HWPX);
        float s = 0.f;
        for (int i = threadIdx.x; i < HWPX / 4; i += 256) {
            float4 v = p[i];
            s += (v.x + v.y) + (v.z + v.w);
        }
        #pragma unroll
        for (int off = 32; off > 0; off >>= 1) s += __shfl_down(s, off);
        __shared__ float ls[4];
        if ((threadIdx.x & 63) == 0) ls[threadIdx.x >> 6] = s;
        __syncthreads();
        if (threadIdx.x == 0) pooled[blk] = ((ls[0] + ls[1]) + (ls[2] + ls[3])) * (1.0f / (float)HWPX);
    } else {
        int i = (blk - BB * CC) * 256 + threadIdx.x;
        W1b[i] = (__bf16)W1[i];
        W2b[i] = (__bf16)W2[i];
    }
}

__global__ void gate_kernel(const float* __restrict__ pooled,
                            const float* __restrict__ Wg,
                            const float* __restrict__ bg,
                            int* __restrict__ gidx, float* __restrict__ gw) {
    int b = threadIdx.x;
    if (b >= BB) return;
    float logits[EE];
    #pragma unroll
    for (int e = 0; e < EE; ++e) logits[e] = bg[e];
    for (int c = 0; c < CC; ++c) {
        float pv = pooled[b * CC + c];
        #pragma unroll
        for (int e = 0; e < EE; ++e) logits[e] = fmaf(pv, Wg[c * EE + e], logits[e]);
    }
    float m = logits[0];
    #pragma unroll
    for (int e = 1; e < EE; ++e) m = fmaxf(m, logits[e]);
    float wv[EE]; float den = 0.f;
    #pragma unroll
    for (int e = 0; e < EE; ++e) { wv[e] = expf(logits[e] - m); den += wv[e]; }
    float inv = 1.0f / den;
    #pragma unroll
    for (int e = 0; e < EE; ++e) wv[e] *= inv;
    int i0 = 0;
    #pragma unroll
    for (int e = 1; e < EE; ++e) if (wv[e] > wv[i0]) i0 = e;
    int i1 = -1;
    #pragma unroll
    for (int e = 0; e < EE; ++e) {
        if (e == i0) continue;
        if (i1 < 0 || wv[e] > wv[i1]) i1 = e;
    }
    gidx[b * 2 + 0] = i0; gidx[b * 2 + 1] = i1;
    gw[b * 2 + 0] = wv[i0]; gw[b * 2 + 1] = wv[i1];
}

__global__ __launch_bounds__(256) void moe_main_fb(
    const float* __restrict__ x, const float* __restrict__ kvec,
    const __bf16* __restrict__ W1b, const float* __restrict__ b1,
    const __bf16* __restrict__ W2b, const float* __restrict__ b2,
    const int* __restrict__ gidx, const float* __restrict__ gw,
    float* __restrict__ out) {

    __shared__ unsigned int LX[64 * 32];
    __shared__ unsigned int LH0[64 * 32];
    __shared__ unsigned int LH1[64 * 32];

    const int blk = blockIdx.x;
    const int b = blk >> 8;
    const int P0 = (blk & 255) << 6;
    const int t = threadIdx.x;
    const int w = t >> 6;
    const int l = t & 63;
    const int g = l >> 4;
    const int l15 = l & 15;
    const int arow = 16 * w + l15;
    const int r0w = 16 * w + 4 * g;
    const int d0 = 8 * w + 2 * g;

    const int e0 = __builtin_amdgcn_readfirstlane(gidx[b * 2 + 0]);
    const int e1 = __builtin_amdgcn_readfirstlane(gidx[b * 2 + 1]);
    const float wgt0 = gw[b * 2 + 0];
    const float wgt1 = gw[b * 2 + 1];

    bf16x8 a1f[2][2], a2f[2][2];
    #pragma unroll
    for (int ks = 0; ks < 2; ++ks) {
        a1f[0][ks] = *(const bf16x8*)(W1b + e0 * CC * CC + arow * CC + ks * 32 + g * 8);
        a1f[1][ks] = *(const bf16x8*)(W1b + e1 * CC * CC + arow * CC + ks * 32 + g * 8);
        a2f[0][ks] = *(const bf16x8*)(W2b + e0 * CC * CC + arow * CC + ks * 32 + g * 8);
        a2f[1][ks] = *(const bf16x8*)(W2b + e1 * CC * CC + arow * CC + ks * 32 + g * 8);
    }
    const f32x4 b1v0 = *(const f32x4*)(b1 + e0 * CC + r0w);
    const f32x4 b1v1 = *(const f32x4*)(b1 + e1 * CC + r0w);
    const f32x4 b2v0 = *(const f32x4*)(b2 + e0 * CC + r0w);
    const f32x4 b2v1 = *(const f32x4*)(b2 + e1 * CC + r0w);
    const f32x4 kk   = *(const f32x4*)(kvec + b * CC + r0w);
    float bsum[4];
    #pragma unroll
    for (int j = 0; j < 4; ++j) bsum[j] = fmaf(wgt0, b2v0[j], wgt1 * b2v1[j]);

    const float* xb = x + b * CC * HWPX;
    const int obase = r0w * HWPX + P0 + l15;
    float xc[16];
    #pragma unroll
    for (int cb = 0; cb < 4; ++cb)
        #pragma unroll
        for (int j = 0; j < 4; ++j)
            xc[cb * 4 + j] = xb[obase + j * HWPX + cb * 16];

    #pragma unroll
    for (int cb = 0; cb < 4; ++cb) {
        uint2 pk;
        pk.x = packbf2(xc[cb * 4 + 0], xc[cb * 4 + 1]);
        pk.y = packbf2(xc[cb * 4 + 2], xc[cb * 4 + 3]);
        *(uint2*)&LX[swz(cb * 16 + l15, d0)] = pk;
    }
    __syncthreads();

    const float C1 = -2.302208239f;
    const float C2 = -0.1029434f;

    f32x4 h0[4], h1[4];
    #pragma unroll
    for (int cb = 0; cb < 4; ++cb) {
        bf16x8 bx0 = *(const bf16x8*)&LX[swz(cb * 16 + l15, g * 4)];
        bf16x8 bx1 = *(const bf16x8*)&LX[swz(cb * 16 + l15, 16 + g * 4)];
        h0[cb] = (f32x4){0.f, 0.f, 0.f, 0.f};
        h1[cb] = (f32x4){0.f, 0.f, 0.f, 0.f};
        h0[cb] = __builtin_amdgcn_mfma_f32_16x16x32_bf16(a1f[0][0], bx0, h0[cb], 0, 0, 0);
        h0[cb] = __builtin_amdgcn_mfma_f32_16x16x32_bf16(a1f[0][1], bx1, h0[cb], 0, 0, 0);
        h1[cb] = __builtin_amdgcn_mfma_f32_16x16x32_bf16(a1f[1][0], bx0, h1[cb], 0, 0, 0);
        h1[cb] = __builtin_amdgcn_mfma_f32_16x16x32_bf16(a1f[1][1], bx1, h1[cb], 0, 0, 0);
    }
    #pragma unroll
    for (int cb = 0; cb < 4; ++cb) {
        float hv0[4], hv1[4];
        #pragma unroll
        for (int j = 0; j < 4; ++j) {
            float t0 = (h0[cb][j] + b1v0[j]) * kk[j];
            float ex0 = __builtin_amdgcn_exp2f(t0 * fmaf(C2, t0 * t0, C1));
            hv0[j] = (t0 * wgt0) * __builtin_amdgcn_rcpf(ex0 + 1.f);
            float t1 = (h1[cb][j] + b1v1[j]) * kk[j];
            float ex1 = __builtin_amdgcn_exp2f(t1 * fmaf(C2, t1 * t1, C1));
            hv1[j] = (t1 * wgt1) * __builtin_amdgcn_rcpf(ex1 + 1.f);
        }
        uint2 pk0, pk1;
        pk0.x = packbf2(hv0[0], hv0[1]);
        pk0.y = packbf2(hv0[2], hv0[3]);
        pk1.x = packbf2(hv1[0], hv1[1]);
        pk1.y = packbf2(hv1[2], hv1[3]);
        *(uint2*)&LH0[swz(cb * 16 + l15, d0)] = pk0;
        *(uint2*)&LH1[swz(cb * 16 + l15, d0)] = pk1;
    }
    __syncthreads();

    f32x4 acc[4];
    #pragma unroll
    for (int cb = 0; cb < 4; ++cb) {
        acc[cb] = (f32x4){0.f, 0.f, 0.f, 0.f};
        #pragma unroll
        for (int ks = 0; ks < 2; ++ks) {
            bf16x8 bh0 = *(const bf16x8*)&LH0[swz(cb * 16 + l15, ks * 16 + g * 4)];
            acc[cb] = __builtin_amdgcn_mfma_f32_16x16x32_bf16(a2f[0][ks], bh0, acc[cb], 0, 0, 0);
            bf16x8 bh1 = *(const bf16x8*)&LH1[swz(cb * 16 + l15, ks * 16 + g * 4)];
            acc[cb] = __builtin_amdgcn_mfma_f32_16x16x32_bf16(a2f[1][ks], bh1, acc[cb], 0, 0, 0);
        }
    }

    float* ob = out + b * CC * HWPX;
    #pragma unroll
    for (int cb = 0; cb < 4; ++cb)
        #pragma unroll
        for (int j = 0; j < 4; ++j)
            ob[obase + j * HWPX + cb * 16] = xc[cb * 4 + j] + (acc[cb][j] + bsum[j]);
}

extern "C" void kernel_launch(void* const* d_in, const int* in_sizes, int n_in,
                              void* d_out, int out_size, void* d_ws, size_t ws_size,
                              hipStream_t stream) {
    const float* x  = (const float*)d_in[0];
    const float* k  = (const float*)d_in[1];
    const float* Wg = (const float*)d_in[2];
    const float* bg = (const float*)d_in[3];
    const float* W1 = (const float*)d_in[4];
    const float* b1 = (const float*)d_in[5];
    const float* W2 = (const float*)d_in[6];
    const float* b2 = (const float*)d_in[7];
    float* out = (float*)d_out;

    // fused-path workspace layout (bytes):
    //   0     : tick (4)
    //   1024  : cnt[16]  stride 64
    //   2048  : flag[16] stride 64
    //   3072  : gidx[32] (128)
    //   3328  : gw[32]   (128)
    //   4096  : partial[4096][64] f32 (1 MiB)
    const size_t need = 4096 + (size_t)4096 * 64 * 4;

    if (ws_size >= need) {
        unsigned* tick   = (unsigned*)d_ws;
        unsigned* cnt    = (unsigned*)((char*)d_ws + 1024);
        unsigned* flag   = (unsigned*)((char*)d_ws + 2048);
        int*      gidx   = (int*)((char*)d_ws + 3072);
        float*    gw     = (float*)((char*)d_ws + 3328);
        float*    part   = (float*)((char*)d_ws + 4096);
        hipMemsetAsync(d_ws, 0, 3072, stream);
        moe_fused<<<BB * 256, 256, 0, stream>>>(x, k, Wg, bg, W1, b1, W2, b2, out,
                                                tick, cnt, flag, gidx, gw, part);
    } else {
        float*  pooled = (float*)d_ws;
        int*    gidx   = (int*)((char*)d_ws + 4096);
        float*  gw     = (float*)((char*)d_ws + 4096 + 128);
        __bf16* W1b    = (__bf16*)((char*)d_ws + 8192);
        __bf16* W2b    = (__bf16*)((char*)d_ws + 8192 + 65536);
        pool_conv_kernel<<<BB * CC + EE * CC * CC / 256, 256, 0, stream>>>(x, pooled, W1, W2, W1b, W2b);
        gate_kernel<<<1, 64, 0, stream>>>(pooled, Wg, bg, gidx, gw);
        moe_main_fb<<<BB * 256, 256, 0, stream>>>(x, k, W1b, b1, W2b, b2, gidx, gw, out);
    }
}

// Round 15
// 86.984 us; speedup vs baseline: 7.3953x; 7.3953x over previous
//
#include <hip/hip_runtime.h>
#include <hip/hip_bf16.h>

// MoE layer, MI355X gfx950. B=16, C=64, H=W=128, E=8, TOPK=2.
// out = x + sum_{s in top2} w_s * (W2_e @ gelu((W1_e @ x + b1_e) * k) + b2_e)
// 2-kernel structure:
//   [pool + wconv + last-block-gate]  ->  [fused top-2 MFMA MLP + residual]
// Gate runs inline in the LAST-finishing pool block (atomic counter; no
// spinning anywhere). moe_main is the proven round-9 pipeline, x loads first.

#define BB 16
#define CC 64
#define EE 8
#define HWPX 16384

typedef __bf16 bf16x8 __attribute__((ext_vector_type(8)));
typedef float f32x4 __attribute__((ext_vector_type(4)));

__device__ __forceinline__ unsigned packbf2(float lo, float hi) {
    // compiler emits v_cvt_pk_bf16_f32 (RNE)
    __bf16 a = (__bf16)lo, b = (__bf16)hi;
    unsigned short ua = __builtin_bit_cast(unsigned short, a);
    unsigned short ub = __builtin_bit_cast(unsigned short, b);
    return ((unsigned)ub << 16) | (unsigned)ua;
}

// XOR-swizzled dword index into a [64 px][32 dword] LDS tile.
// Same involution on write and read; 16B chunks XORed by (px&7).
__device__ __forceinline__ int swz(int px, int d) {
    return px * 32 + ((d & ~3) ^ ((px & 7) << 2)) + (d & 3);
}

// ---------------- kernel 1: pool (blocks 0..1023) + wconv (1024..1151) + gate (last pool block) ----------------
__global__ __launch_bounds__(256) void pool_conv_gate(
    const float* __restrict__ x,
    const float* __restrict__ Wg, const float* __restrict__ bg,
    const float* __restrict__ W1, const float* __restrict__ W2,
    __bf16* __restrict__ W1b, __bf16* __restrict__ W2b,
    float* __restrict__ pooled, unsigned* __restrict__ cnt,
    int* __restrict__ gidx, float* __restrict__ gw) {

    const int blk = blockIdx.x;
    const int t = threadIdx.x;
    __shared__ float ls[4];
    __shared__ unsigned lastFlag;

    if (blk < BB * CC) {
        // ---- pool one (b, c) channel ----
        const float4* p = (const float4*)(x + (size_t)blk * HWPX);
        float s = 0.f;
        for (int i = t; i < HWPX / 4; i += 256) {
            float4 v = p[i];
            s += (v.x + v.y) + (v.z + v.w);
        }
        #pragma unroll
        for (int off = 32; off > 0; off >>= 1) s += __shfl_down(s, off);
        if ((t & 63) == 0) ls[t >> 6] = s;
        __syncthreads();
        if (t == 0) {
            pooled[blk] = ((ls[0] + ls[1]) + (ls[2] + ls[3])) * (1.0f / (float)HWPX);
            __threadfence();
            unsigned old = __hip_atomic_fetch_add(cnt, 1u, __ATOMIC_ACQ_REL, __HIP_MEMORY_SCOPE_AGENT);
            lastFlag = (old == (unsigned)(BB * CC - 1)) ? 1u : 0u;
        }
        __syncthreads();

        // ---- last-finishing pool block computes the gate (no spinning) ----
        if (lastFlag && t < BB) {
            const int b = t;
            float logits[EE];
            #pragma unroll
            for (int e = 0; e < EE; ++e) logits[e] = bg[e];
            for (int c = 0; c < CC; ++c) {
                float pv = pooled[b * CC + c];
                #pragma unroll
                for (int e = 0; e < EE; ++e) logits[e] = fmaf(pv, Wg[c * EE + e], logits[e]);
            }
            float m = logits[0];
            #pragma unroll
            for (int e = 1; e < EE; ++e) m = fmaxf(m, logits[e]);
            float wv[EE]; float den = 0.f;
            #pragma unroll
            for (int e = 0; e < EE; ++e) { wv[e] = expf(logits[e] - m); den += wv[e]; }
            float inv = 1.0f / den;
            #pragma unroll
            for (int e = 0; e < EE; ++e) wv[e] *= inv;
            int i0 = 0;
            #pragma unroll
            for (int e = 1; e < EE; ++e) if (wv[e] > wv[i0]) i0 = e;
            int i1 = -1;
            #pragma unroll
            for (int e = 0; e < EE; ++e) {
                if (e == i0) continue;
                if (i1 < 0 || wv[e] > wv[i1]) i1 = e;
            }
            gidx[b * 2 + 0] = i0; gidx[b * 2 + 1] = i1;
            gw[b * 2 + 0] = wv[i0]; gw[b * 2 + 1] = wv[i1];
        }
    } else {
        // ---- convert W1/W2 slice to bf16 ----
        int i = (blk - BB * CC) * 256 + t;  // 0..32767
        W1b[i] = (__bf16)W1[i];
        W2b[i] = (__bf16)W2[i];
    }
}

// ---------------- kernel 2: fused top-2 expert MLP + residual (MFMA) ----------------
// Grid: 4096 = 16 batches x 256 tiles (64 px). Block: 256 thr = 4 waves.
// Thread (w,g,l15) owns channels 16w+4g..+3 x pixels {16cb+l15}: loads them
// once (f32 residual regs), stages bf16 to LDS, stores the final output.
// 2 barriers; 3 x 8KB swizzled LDS buffers (xT, hT0, hT1).
__global__ __launch_bounds__(256) void moe_main(
    const float* __restrict__ x, const float* __restrict__ kvec,
    const __bf16* __restrict__ W1b, const float* __restrict__ b1,
    const __bf16* __restrict__ W2b, const float* __restrict__ b2,
    const int* __restrict__ gidx, const float* __restrict__ gw,
    float* __restrict__ out) {

    __shared__ unsigned int LX[64 * 32];
    __shared__ unsigned int LH0[64 * 32];
    __shared__ unsigned int LH1[64 * 32];

    const int blk = blockIdx.x;
    const int b = blk >> 8;            // batch
    const int P0 = (blk & 255) << 6;   // tile base pixel
    const int t = threadIdx.x;
    const int w = t >> 6;              // wave id
    const int l = t & 63;
    const int g = l >> 4;              // 16-lane group
    const int l15 = l & 15;

    const int arow = 16 * w + l15;     // A-fragment row (out channel)
    const int r0w = 16 * w + 4 * g;    // this lane's first owned channel
    const int d0 = 8 * w + 2 * g;      // LDS dword col of channels r0w..r0w+3

    // ---- x loads FIRST (longest-latency critical path) ----
    const float* xb = x + b * CC * HWPX;
    const int obase = r0w * HWPX + P0 + l15;
    float xc[16];
    #pragma unroll
    for (int cb = 0; cb < 4; ++cb)
        #pragma unroll
        for (int j = 0; j < 4; ++j)
            xc[cb * 4 + j] = xb[obase + j * HWPX + cb * 16];

    // ---- gate results ----
    const int e0 = __builtin_amdgcn_readfirstlane(gidx[b * 2 + 0]);
    const int e1 = __builtin_amdgcn_readfirstlane(gidx[b * 2 + 1]);
    const float wgt0 = gw[b * 2 + 0];
    const float wgt1 = gw[b * 2 + 1];

    // ---- weight fragments + biases (L2-hot) ----
    bf16x8 a1f[2][2], a2f[2][2];
    #pragma unroll
    for (int ks = 0; ks < 2; ++ks) {
        a1f[0][ks] = *(const bf16x8*)(W1b + e0 * CC * CC + arow * CC + ks * 32 + g * 8);
        a1f[1][ks] = *(const bf16x8*)(W1b + e1 * CC * CC + arow * CC + ks * 32 + g * 8);
        a2f[0][ks] = *(const bf16x8*)(W2b + e0 * CC * CC + arow * CC + ks * 32 + g * 8);
        a2f[1][ks] = *(const bf16x8*)(W2b + e1 * CC * CC + arow * CC + ks * 32 + g * 8);
    }
    const f32x4 b1v0 = *(const f32x4*)(b1 + e0 * CC + r0w);
    const f32x4 b1v1 = *(const f32x4*)(b1 + e1 * CC + r0w);
    const f32x4 b2v0 = *(const f32x4*)(b2 + e0 * CC + r0w);
    const f32x4 b2v1 = *(const f32x4*)(b2 + e1 * CC + r0w);
    const f32x4 kk   = *(const f32x4*)(kvec + b * CC + r0w);
    float bsum[4];
    #pragma unroll
    for (int j = 0; j < 4; ++j) bsum[j] = fmaf(wgt0, b2v0[j], wgt1 * b2v1[j]);

    // ---- stage x to LDS (bf16 pairs, swizzled) ----
    #pragma unroll
    for (int cb = 0; cb < 4; ++cb) {
        uint2 pk;
        pk.x = packbf2(xc[cb * 4 + 0], xc[cb * 4 + 1]);
        pk.y = packbf2(xc[cb * 4 + 2], xc[cb * 4 + 3]);
        *(uint2*)&LX[swz(cb * 16 + l15, d0)] = pk;
    }
    __syncthreads();   // bar A: xT visible

    // ---- x B-fragments + GEMM1 both experts ----
    f32x4 h0[4], h1[4];
    #pragma unroll
    for (int cb = 0; cb < 4; ++cb) {
        bf16x8 bx0 = *(const bf16x8*)&LX[swz(cb * 16 + l15, g * 4)];
        bf16x8 bx1 = *(const bf16x8*)&LX[swz(cb * 16 + l15, 16 + g * 4)];
        h0[cb] = (f32x4){0.f, 0.f, 0.f, 0.f};
        h1[cb] = (f32x4){0.f, 0.f, 0.f, 0.f};
        h0[cb] = __builtin_amdgcn_mfma_f32_16x16x32_bf16(a1f[0][0], bx0, h0[cb], 0, 0, 0);
        h0[cb] = __builtin_amdgcn_mfma_f32_16x16x32_bf16(a1f[0][1], bx1, h0[cb], 0, 0, 0);
        h1[cb] = __builtin_amdgcn_mfma_f32_16x16x32_bf16(a1f[1][0], bx0, h1[cb], 0, 0, 0);
        h1[cb] = __builtin_amdgcn_mfma_f32_16x16x32_bf16(a1f[1][1], bx1, h1[cb], 0, 0, 0);
    }

    // gelu sigmoid-form: gelu(t) = t * rcp(1 + exp2(t*(C1 + C2*t^2)))
    const float C1 = -2.302208239f;    // -2*log2(e)*0.7978845608
    const float C2 = -0.1029434f;      // C1 * 0.044715

    // ---- gelu + pack both experts (gate weights folded in), write hT0/hT1 ----
    #pragma unroll
    for (int cb = 0; cb < 4; ++cb) {
        float hv0[4], hv1[4];
        #pragma unroll
        for (int j = 0; j < 4; ++j) {
            float t0 = (h0[cb][j] + b1v0[j]) * kk[j];
            float ex0 = __builtin_amdgcn_exp2f(t0 * fmaf(C2, t0 * t0, C1));
            hv0[j] = (t0 * wgt0) * __builtin_amdgcn_rcpf(ex0 + 1.f);
            float t1 = (h1[cb][j] + b1v1[j]) * kk[j];
            float ex1 = __builtin_amdgcn_exp2f(t1 * fmaf(C2, t1 * t1, C1));
            hv1[j] = (t1 * wgt1) * __builtin_amdgcn_rcpf(ex1 + 1.f);
        }
        uint2 pk0, pk1;
        pk0.x = packbf2(hv0[0], hv0[1]);
        pk0.y = packbf2(hv0[2], hv0[3]);
        pk1.x = packbf2(hv1[0], hv1[1]);
        pk1.y = packbf2(hv1[2], hv1[3]);
        *(uint2*)&LH0[swz(cb * 16 + l15, d0)] = pk0;
        *(uint2*)&LH1[swz(cb * 16 + l15, d0)] = pk1;
    }
    __syncthreads();   // bar B: hT0 + hT1 visible

    // ---- GEMM2 both experts ----
    f32x4 acc[4];
    #pragma unroll
    for (int cb = 0; cb < 4; ++cb) {
        acc[cb] = (f32x4){0.f, 0.f, 0.f, 0.f};
        #pragma unroll
        for (int ks = 0; ks < 2; ++ks) {
            bf16x8 bh0 = *(const bf16x8*)&LH0[swz(cb * 16 + l15, ks * 16 + g * 4)];
            acc[cb] = __builtin_amdgcn_mfma_f32_16x16x32_bf16(a2f[0][ks], bh0, acc[cb], 0, 0, 0);
            bf16x8 bh1 = *(const bf16x8*)&LH1[swz(cb * 16 + l15, ks * 16 + g * 4)];
            acc[cb] = __builtin_amdgcn_mfma_f32_16x16x32_bf16(a2f[1][ks], bh1, acc[cb], 0, 0, 0);
        }
    }

    // ---- epilogue: out = x(f32 regs) + acc + gated b2 ----
    float* ob = out + b * CC * HWPX;
    #pragma unroll
    for (int cb = 0; cb < 4; ++cb)
        #pragma unroll
        for (int j = 0; j < 4; ++j)
            ob[obase + j * HWPX + cb * 16] = xc[cb * 4 + j] + (acc[cb][j] + bsum[j]);
}

extern "C" void kernel_launch(void* const* d_in, const int* in_sizes, int n_in,
                              void* d_out, int out_size, void* d_ws, size_t ws_size,
                              hipStream_t stream) {
    const float* x  = (const float*)d_in[0];
    const float* k  = (const float*)d_in[1];
    const float* Wg = (const float*)d_in[2];
    const float* bg = (const float*)d_in[3];
    const float* W1 = (const float*)d_in[4];
    const float* b1 = (const float*)d_in[5];
    const float* W2 = (const float*)d_in[6];
    const float* b2 = (const float*)d_in[7];
    float* out = (float*)d_out;

    // workspace layout (bytes):
    //   0     : cnt (4; zeroed each call)
    //   1024  : pooled[1024] f32 (4 KiB)
    //   8192  : gidx[32] (128)
    //   8320  : gw[32]   (128)
    //   16384 : W1b bf16 (64 KiB)
    //   81920 : W2b bf16 (64 KiB)
    unsigned* cnt    = (unsigned*)d_ws;
    float*    pooled = (float*)((char*)d_ws + 1024);
    int*      gidx   = (int*)((char*)d_ws + 8192);
    float*    gw     = (float*)((char*)d_ws + 8320);
    __bf16*   W1b    = (__bf16*)((char*)d_ws + 16384);
    __bf16*   W2b    = (__bf16*)((char*)d_ws + 16384 + 65536);

    hipMemsetAsync(d_ws, 0, 64, stream);
    pool_conv_gate<<<BB * CC + EE * CC * CC / 256, 256, 0, stream>>>(
        x, Wg, bg, W1, W2, W1b, W2b, pooled, cnt, gidx, gw);
    moe_main<<<BB * 256, 256, 0, stream>>>(x, k, W1b, b1, W2b, b2, gidx, gw, out);
}

// Round 16
// 51.903 us; speedup vs baseline: 12.3938x; 1.6759x over previous
//
#include <hip/hip_runtime.h>
#include <hip/hip_bf16.h>

// MoE layer, MI355X gfx950. B=16, C=64, H=W=128, E=8, TOPK=2.
// out = x + sum_{s in top2} w_s * (W2_e @ gelu((W1_e @ x + b1_e) * k) + b2_e)
// 3-kernel structure (kernel boundary = the cheap fence; NO device atomics):
//   pool+wconv  ->  gate  ->  fused top-2 MFMA MLP + residual.
// moe_main issues its x loads FIRST (round-15 discovery: 33 -> ~14 us).

#define BB 16
#define CC 64
#define EE 8
#define HWPX 16384

typedef __bf16 bf16x8 __attribute__((ext_vector_type(8)));
typedef float f32x4 __attribute__((ext_vector_type(4)));

__device__ __forceinline__ unsigned packbf2(float lo, float hi) {
    // compiler emits v_cvt_pk_bf16_f32 (RNE)
    __bf16 a = (__bf16)lo, b = (__bf16)hi;
    unsigned short ua = __builtin_bit_cast(unsigned short, a);
    unsigned short ub = __builtin_bit_cast(unsigned short, b);
    return ((unsigned)ub << 16) | (unsigned)ua;
}

// XOR-swizzled dword index into a [64 px][32 dword] LDS tile.
// Same involution on write and read; 16B chunks XORed by (px&7).
__device__ __forceinline__ int swz(int px, int d) {
    return px * 32 + ((d & ~3) ^ ((px & 7) << 2)) + (d & 3);
}

// ---------------- kernel 1: global avg pool (blocks 0..1023) + W-conv (1024..1151) ----------------
__global__ __launch_bounds__(256) void pool_conv_kernel(
    const float* __restrict__ x, float* __restrict__ pooled,
    const float* __restrict__ W1, const float* __restrict__ W2,
    __bf16* __restrict__ W1b, __bf16* __restrict__ W2b) {
    int blk = blockIdx.x;
    if (blk < BB * CC) {
        const float4* p = (const float4*)(x + (size_t)blk * HWPX);
        float s = 0.f;
        for (int i = threadIdx.x; i < HWPX / 4; i += 256) {
            float4 v = p[i];
            s += (v.x + v.y) + (v.z + v.w);
        }
        #pragma unroll
        for (int off = 32; off > 0; off >>= 1) s += __shfl_down(s, off);
        __shared__ float ls[4];
        if ((threadIdx.x & 63) == 0) ls[threadIdx.x >> 6] = s;
        __syncthreads();
        if (threadIdx.x == 0) pooled[blk] = ((ls[0] + ls[1]) + (ls[2] + ls[3])) * (1.0f / (float)HWPX);
    } else {
        int i = (blk - BB * CC) * 256 + threadIdx.x;  // 0..32767
        W1b[i] = (__bf16)W1[i];
        W2b[i] = (__bf16)W2[i];
    }
}

// ---------------- kernel 2: gate logits + softmax + top2 ----------------
__global__ void gate_kernel(const float* __restrict__ pooled,
                            const float* __restrict__ Wg,
                            const float* __restrict__ bg,
                            int* __restrict__ gidx, float* __restrict__ gw) {
    int b = threadIdx.x;
    if (b >= BB) return;
    float logits[EE];
    #pragma unroll
    for (int e = 0; e < EE; ++e) logits[e] = bg[e];
    for (int c = 0; c < CC; ++c) {
        float pv = pooled[b * CC + c];
        #pragma unroll
        for (int e = 0; e < EE; ++e) logits[e] = fmaf(pv, Wg[c * EE + e], logits[e]);
    }
    float m = logits[0];
    #pragma unroll
    for (int e = 1; e < EE; ++e) m = fmaxf(m, logits[e]);
    float w[EE]; float den = 0.f;
    #pragma unroll
    for (int e = 0; e < EE; ++e) { w[e] = expf(logits[e] - m); den += w[e]; }
    float inv = 1.0f / den;
    #pragma unroll
    for (int e = 0; e < EE; ++e) w[e] *= inv;
    int i0 = 0;
    #pragma unroll
    for (int e = 1; e < EE; ++e) if (w[e] > w[i0]) i0 = e;
    int i1 = -1;
    #pragma unroll
    for (int e = 0; e < EE; ++e) {
        if (e == i0) continue;
        if (i1 < 0 || w[e] > w[i1]) i1 = e;
    }
    gidx[b * 2 + 0] = i0; gidx[b * 2 + 1] = i1;
    gw[b * 2 + 0] = w[i0]; gw[b * 2 + 1] = w[i1];
}

// ---------------- kernel 3: fused top-2 expert MLP + residual (MFMA) ----------------
// Grid: 4096 = 16 batches x 256 tiles (64 px). Block: 256 thr = 4 waves.
// Thread (w,g,l15) owns channels 16w+4g..+3 x pixels {16cb+l15}: loads them
// once (f32 residual regs), stages bf16 to LDS, stores the final output.
// x loads issue FIRST (critical-path HBM latency overlaps everything else).
// 2 barriers; 3 x 8KB swizzled LDS buffers (xT, hT0, hT1).
__global__ __launch_bounds__(256) void moe_main(
    const float* __restrict__ x, const float* __restrict__ kvec,
    const __bf16* __restrict__ W1b, const float* __restrict__ b1,
    const __bf16* __restrict__ W2b, const float* __restrict__ b2,
    const int* __restrict__ gidx, const float* __restrict__ gw,
    float* __restrict__ out) {

    __shared__ unsigned int LX[64 * 32];
    __shared__ unsigned int LH0[64 * 32];
    __shared__ unsigned int LH1[64 * 32];

    const int blk = blockIdx.x;
    const int b = blk >> 8;            // batch
    const int P0 = (blk & 255) << 6;   // tile base pixel
    const int t = threadIdx.x;
    const int w = t >> 6;              // wave id
    const int l = t & 63;
    const int g = l >> 4;              // 16-lane group
    const int l15 = l & 15;

    const int arow = 16 * w + l15;     // A-fragment row (out channel)
    const int r0w = 16 * w + 4 * g;    // this lane's first owned channel
    const int d0 = 8 * w + 2 * g;      // LDS dword col of channels r0w..r0w+3

    // ---- x loads FIRST (longest-latency critical path) ----
    const float* xb = x + b * CC * HWPX;
    const int obase = r0w * HWPX + P0 + l15;
    float xc[16];
    #pragma unroll
    for (int cb = 0; cb < 4; ++cb)
        #pragma unroll
        for (int j = 0; j < 4; ++j)
            xc[cb * 4 + j] = xb[obase + j * HWPX + cb * 16];

    // ---- gate results ----
    const int e0 = __builtin_amdgcn_readfirstlane(gidx[b * 2 + 0]);
    const int e1 = __builtin_amdgcn_readfirstlane(gidx[b * 2 + 1]);
    const float wgt0 = gw[b * 2 + 0];
    const float wgt1 = gw[b * 2 + 1];

    // ---- weight fragments + biases (L2-hot) ----
    bf16x8 a1f[2][2], a2f[2][2];
    #pragma unroll
    for (int ks = 0; ks < 2; ++ks) {
        a1f[0][ks] = *(const bf16x8*)(W1b + e0 * CC * CC + arow * CC + ks * 32 + g * 8);
        a1f[1][ks] = *(const bf16x8*)(W1b + e1 * CC * CC + arow * CC + ks * 32 + g * 8);
        a2f[0][ks] = *(const bf16x8*)(W2b + e0 * CC * CC + arow * CC + ks * 32 + g * 8);
        a2f[1][ks] = *(const bf16x8*)(W2b + e1 * CC * CC + arow * CC + ks * 32 + g * 8);
    }
    const f32x4 b1v0 = *(const f32x4*)(b1 + e0 * CC + r0w);
    const f32x4 b1v1 = *(const f32x4*)(b1 + e1 * CC + r0w);
    const f32x4 b2v0 = *(const f32x4*)(b2 + e0 * CC + r0w);
    const f32x4 b2v1 = *(const f32x4*)(b2 + e1 * CC + r0w);
    const f32x4 kk   = *(const f32x4*)(kvec + b * CC + r0w);
    float bsum[4];
    #pragma unroll
    for (int j = 0; j < 4; ++j) bsum[j] = fmaf(wgt0, b2v0[j], wgt1 * b2v1[j]);

    // ---- stage x to LDS (bf16 pairs, swizzled) ----
    #pragma unroll
    for (int cb = 0; cb < 4; ++cb) {
        uint2 pk;
        pk.x = packbf2(xc[cb * 4 + 0], xc[cb * 4 + 1]);
        pk.y = packbf2(xc[cb * 4 + 2], xc[cb * 4 + 3]);
        *(uint2*)&LX[swz(cb * 16 + l15, d0)] = pk;
    }
    __syncthreads();   // bar A: xT visible

    // ---- x B-fragments + GEMM1 both experts ----
    f32x4 h0[4], h1[4];
    #pragma unroll
    for (int cb = 0; cb < 4; ++cb) {
        bf16x8 bx0 = *(const bf16x8*)&LX[swz(cb * 16 + l15, g * 4)];
        bf16x8 bx1 = *(const bf16x8*)&LX[swz(cb * 16 + l15, 16 + g * 4)];
        h0[cb] = (f32x4){0.f, 0.f, 0.f, 0.f};
        h1[cb] = (f32x4){0.f, 0.f, 0.f, 0.f};
        h0[cb] = __builtin_amdgcn_mfma_f32_16x16x32_bf16(a1f[0][0], bx0, h0[cb], 0, 0, 0);
        h0[cb] = __builtin_amdgcn_mfma_f32_16x16x32_bf16(a1f[0][1], bx1, h0[cb], 0, 0, 0);
        h1[cb] = __builtin_amdgcn_mfma_f32_16x16x32_bf16(a1f[1][0], bx0, h1[cb], 0, 0, 0);
        h1[cb] = __builtin_amdgcn_mfma_f32_16x16x32_bf16(a1f[1][1], bx1, h1[cb], 0, 0, 0);
    }

    // gelu sigmoid-form: gelu(t) = t * rcp(1 + exp2(t*(C1 + C2*t^2)))
    const float C1 = -2.302208239f;    // -2*log2(e)*0.7978845608
    const float C2 = -0.1029434f;      // C1 * 0.044715

    // ---- gelu + pack both experts (gate weights folded in), write hT0/hT1 ----
    #pragma unroll
    for (int cb = 0; cb < 4; ++cb) {
        float hv0[4], hv1[4];
        #pragma unroll
        for (int j = 0; j < 4; ++j) {
            float t0 = (h0[cb][j] + b1v0[j]) * kk[j];
            float ex0 = __builtin_amdgcn_exp2f(t0 * fmaf(C2, t0 * t0, C1));
            hv0[j] = (t0 * wgt0) * __builtin_amdgcn_rcpf(ex0 + 1.f);
            float t1 = (h1[cb][j] + b1v1[j]) * kk[j];
            float ex1 = __builtin_amdgcn_exp2f(t1 * fmaf(C2, t1 * t1, C1));
            hv1[j] = (t1 * wgt1) * __builtin_amdgcn_rcpf(ex1 + 1.f);
        }
        uint2 pk0, pk1;
        pk0.x = packbf2(hv0[0], hv0[1]);
        pk0.y = packbf2(hv0[2], hv0[3]);
        pk1.x = packbf2(hv1[0], hv1[1]);
        pk1.y = packbf2(hv1[2], hv1[3]);
        *(uint2*)&LH0[swz(cb * 16 + l15, d0)] = pk0;
        *(uint2*)&LH1[swz(cb * 16 + l15, d0)] = pk1;
    }
    __syncthreads();   // bar B: hT0 + hT1 visible

    // ---- GEMM2 both experts ----
    f32x4 acc[4];
    #pragma unroll
    for (int cb = 0; cb < 4; ++cb) {
        acc[cb] = (f32x4){0.f, 0.f, 0.f, 0.f};
        #pragma unroll
        for (int ks = 0; ks < 2; ++ks) {
            bf16x8 bh0 = *(const bf16x8*)&LH0[swz(cb * 16 + l15, ks * 16 + g * 4)];
            acc[cb] = __builtin_amdgcn_mfma_f32_16x16x32_bf16(a2f[0][ks], bh0, acc[cb], 0, 0, 0);
            bf16x8 bh1 = *(const bf16x8*)&LH1[swz(cb * 16 + l15, ks * 16 + g * 4)];
            acc[cb] = __builtin_amdgcn_mfma_f32_16x16x32_bf16(a2f[1][ks], bh1, acc[cb], 0, 0, 0);
        }
    }

    // ---- epilogue: out = x(f32 regs) + acc + gated b2 ----
    float* ob = out + b * CC * HWPX;
    #pragma unroll
    for (int cb = 0; cb < 4; ++cb)
        #pragma unroll
        for (int j = 0; j < 4; ++j)
            ob[obase + j * HWPX + cb * 16] = xc[cb * 4 + j] + (acc[cb][j] + bsum[j]);
}

extern "C" void kernel_launch(void* const* d_in, const int* in_sizes, int n_in,
                              void* d_out, int out_size, void* d_ws, size_t ws_size,
                              hipStream_t stream) {
    const float* x  = (const float*)d_in[0];
    const float* k  = (const float*)d_in[1];
    const float* Wg = (const float*)d_in[2];
    const float* bg = (const float*)d_in[3];
    const float* W1 = (const float*)d_in[4];
    const float* b1 = (const float*)d_in[5];
    const float* W2 = (const float*)d_in[6];
    const float* b2 = (const float*)d_in[7];
    float* out = (float*)d_out;

    // workspace layout
    float*  pooled = (float*)d_ws;                          // 4 KiB
    int*    gidx   = (int*)((char*)d_ws + 4096);            // 128 B
    float*  gw     = (float*)((char*)d_ws + 4096 + 128);    // 128 B
    __bf16* W1b    = (__bf16*)((char*)d_ws + 8192);         // 64 KiB
    __bf16* W2b    = (__bf16*)((char*)d_ws + 8192 + 65536); // 64 KiB

    pool_conv_kernel<<<BB * CC + EE * CC * CC / 256, 256, 0, stream>>>(x, pooled, W1, W2, W1b, W2b);
    gate_kernel<<<1, 64, 0, stream>>>(pooled, Wg, bg, gidx, gw);
    moe_main<<<BB * 256, 256, 0, stream>>>(x, k, W1b, b1, W2b, b2, gidx, gw, out);
}